// Round 10
// baseline (151.354 us; speedup 1.0000x reference)
//
#include <hip/hip_runtime.h>

#define MD 1024
#define L 128
#define LN_EPS 1e-5f

typedef __attribute__((ext_vector_type(8))) short bh8;   // 8 x bf16 (4 VGPR)
typedef __attribute__((ext_vector_type(4))) float fx4;   // MFMA accumulator
typedef __attribute__((ext_vector_type(4))) float f4;    // vector float4

__device__ __forceinline__ unsigned short f2bf(float x) {
  unsigned int u = __float_as_uint(x);
  u = (u + 0x7FFFu + ((u >> 16) & 1u)) >> 16;  // RNE
  return (unsigned short)u;
}

// ---------------------------------------------------------------------------
// fp32 -> bf16 convert: z picks array {query,key,value,Wq,Wk,Wv,Wo}
// ---------------------------------------------------------------------------
__global__ __launch_bounds__(256) void cvt_bf16(
    const float* s0, const float* s1, const float* s2, const float* s3,
    const float* s4, const float* s5, const float* s6, unsigned short* d0,
    unsigned short* d1, unsigned short* d2, unsigned short* d3,
    unsigned short* d4, unsigned short* d5, unsigned short* d6) {
  const float* s;
  unsigned short* d;
  int n;
  switch (blockIdx.z) {
    case 0: s = s0; d = d0; n = 524288; break;
    case 1: s = s1; d = d1; n = 524288; break;
    case 2: s = s2; d = d2; n = 524288; break;
    case 3: s = s3; d = d3; n = 1048576; break;
    case 4: s = s4; d = d4; n = 1048576; break;
    case 5: s = s5; d = d5; n = 1048576; break;
    default: s = s6; d = d6; n = 1048576; break;
  }
  const int idx = (blockIdx.x * 256 + threadIdx.x) * 8;
  if (idx < n) {
    const float4 a = *(const float4*)&s[idx];
    const float4 b = *(const float4*)&s[idx + 4];
    uint4 o;
    o.x = (unsigned int)f2bf(a.x) | ((unsigned int)f2bf(a.y) << 16);
    o.y = (unsigned int)f2bf(a.z) | ((unsigned int)f2bf(a.w) << 16);
    o.z = (unsigned int)f2bf(b.x) | ((unsigned int)f2bf(b.y) << 16);
    o.w = (unsigned int)f2bf(b.z) | ((unsigned int)f2bf(b.w) << 16);
    *(uint4*)&d[idx] = o;
  }
}

// ---------------------------------------------------------------------------
// bf16 MFMA GEMM: out[r][c] = sum_m A[r][m] * W[c][m] + bias[c]
// A: [512][1024] bf16, W: [1024][1024] bf16 (row = output col).
// 64x64 tile / block, 4 waves (2x2), each wave 32x32 via 2x2 16x16x32 frags.
// ---------------------------------------------------------------------------
__device__ __forceinline__ void mfma_gemm_body(
    const unsigned short* __restrict__ A, const unsigned short* __restrict__ W,
    const float* __restrict__ bias, float* __restrict__ out,
    unsigned short* __restrict__ outb) {
  __shared__ short As[64][40];
  __shared__ short Bs[64][40];
  const int t = threadIdx.x;
  const int row0 = blockIdx.x * 64;
  const int col0 = blockIdx.y * 64;
  const int l = t & 63;
  const int w = t >> 6;
  const int wr = (w >> 1) * 32;
  const int wc = (w & 1) * 32;
  const int srow = t >> 2;       // 0..63
  const int skg = (t & 3) * 8;   // 0,8,16,24
  const int fr = l & 15;
  const int fq = (l >> 4) * 8;

  fx4 z = {0.f, 0.f, 0.f, 0.f};
  fx4 acc[2][2];
  acc[0][0] = z; acc[0][1] = z; acc[1][0] = z; acc[1][1] = z;

  for (int k0 = 0; k0 < MD; k0 += 32) {
    const uint4 av = *(const uint4*)&A[(size_t)(row0 + srow) * MD + k0 + skg];
    const uint4 bv = *(const uint4*)&W[(size_t)(col0 + srow) * MD + k0 + skg];
    __syncthreads();
    *(uint4*)&As[srow][skg] = av;
    *(uint4*)&Bs[srow][skg] = bv;
    __syncthreads();
    const bh8 a0 = *(const bh8*)&As[wr + fr][fq];
    const bh8 a1 = *(const bh8*)&As[wr + 16 + fr][fq];
    const bh8 b0 = *(const bh8*)&Bs[wc + fr][fq];
    const bh8 b1 = *(const bh8*)&Bs[wc + 16 + fr][fq];
    acc[0][0] = __builtin_amdgcn_mfma_f32_16x16x32_bf16(a0, b0, acc[0][0], 0, 0, 0);
    acc[0][1] = __builtin_amdgcn_mfma_f32_16x16x32_bf16(a0, b1, acc[0][1], 0, 0, 0);
    acc[1][0] = __builtin_amdgcn_mfma_f32_16x16x32_bf16(a1, b0, acc[1][0], 0, 0, 0);
    acc[1][1] = __builtin_amdgcn_mfma_f32_16x16x32_bf16(a1, b1, acc[1][1], 0, 0, 0);
  }

  const int fq4 = (l >> 4) * 4;
#pragma unroll
  for (int m = 0; m < 2; m++)
#pragma unroll
    for (int n = 0; n < 2; n++) {
      const int col = col0 + wc + n * 16 + fr;
      const float bval = bias[col];
#pragma unroll
      for (int r = 0; r < 4; r++) {
        const int row = row0 + wr + m * 16 + fq4 + r;
        const float v = acc[m][n][r] + bval;
        if (out) out[(size_t)row * MD + col] = v;
        if (outb) outb[(size_t)row * MD + col] = f2bf(v);
      }
    }
}

__global__ __launch_bounds__(256) void qkv_mfma(
    const unsigned short* Aq, const unsigned short* Ak,
    const unsigned short* Av, const unsigned short* Wq,
    const unsigned short* Wk, const unsigned short* Wv, const float* bq,
    const float* bk, const float* bv, float* qo, float* ko, float* vo,
    unsigned short* qb, unsigned short* kb) {
  if (blockIdx.z == 0) mfma_gemm_body(Aq, Wq, bq, qo, qb);
  else if (blockIdx.z == 1) mfma_gemm_body(Ak, Wk, bk, ko, kb);
  else mfma_gemm_body(Av, Wv, bv, vo, nullptr);
}

__global__ __launch_bounds__(256) void o_mfma(const unsigned short* A,
                                              const unsigned short* W,
                                              const float* bias, float* out) {
  mfma_gemm_body(A, W, bias, out, nullptr);
}

// ---------------------------------------------------------------------------
// S1[g,i,j] = sum_d q[g,i,d]*k[g,j,d], one block per g.
// The .reshape(B*H,-1,d) view is FLAT: q[g][i][d] = qb_flat[g*16384+i*128+d],
// i.e. per-g a contiguous [128][128] bf16 tile at qb + g*16384.
// ---------------------------------------------------------------------------
__global__ __launch_bounds__(256) void qk_mfma(const unsigned short* __restrict__ qb,
                                               const unsigned short* __restrict__ kb,
                                               float* __restrict__ S1) {
  __shared__ short Qs[128][40];
  __shared__ short Ks[128][40];
  const int g = blockIdx.x;
  const int t = threadIdx.x;
  const int l = t & 63;
  const int w = t >> 6;
  const unsigned short* qg = qb + (size_t)g * 16384;
  const unsigned short* kg = kb + (size_t)g * 16384;
  const int srow = t >> 1;        // 0..127
  const int sh = (t & 1) * 16;    // 0 / 16
  const int fr = l & 15;
  const int fq = (l >> 4) * 8;

  fx4 z = {0.f, 0.f, 0.f, 0.f};
  fx4 acc[2][8];
#pragma unroll
  for (int m = 0; m < 2; m++)
#pragma unroll
    for (int n = 0; n < 8; n++) acc[m][n] = z;

  for (int d0 = 0; d0 < 128; d0 += 32) {
    const size_t off = (size_t)srow * 128 + d0 + sh;
    const uint4 q0 = *(const uint4*)&qg[off];
    const uint4 q1 = *(const uint4*)&qg[off + 8];
    const uint4 k0 = *(const uint4*)&kg[off];
    const uint4 k1 = *(const uint4*)&kg[off + 8];
    __syncthreads();
    *(uint4*)&Qs[srow][sh] = q0;
    *(uint4*)&Qs[srow][sh + 8] = q1;
    *(uint4*)&Ks[srow][sh] = k0;
    *(uint4*)&Ks[srow][sh + 8] = k1;
    __syncthreads();
    const bh8 a0 = *(const bh8*)&Qs[w * 32 + fr][fq];
    const bh8 a1 = *(const bh8*)&Qs[w * 32 + 16 + fr][fq];
#pragma unroll
    for (int n = 0; n < 8; n++) {
      const bh8 b = *(const bh8*)&Ks[n * 16 + fr][fq];
      acc[0][n] = __builtin_amdgcn_mfma_f32_16x16x32_bf16(a0, b, acc[0][n], 0, 0, 0);
      acc[1][n] = __builtin_amdgcn_mfma_f32_16x16x32_bf16(a1, b, acc[1][n], 0, 0, 0);
    }
  }

  const int fq4 = (l >> 4) * 4;
#pragma unroll
  for (int m = 0; m < 2; m++)
#pragma unroll
    for (int n = 0; n < 8; n++)
#pragma unroll
      for (int r = 0; r < 4; r++) {
        const int i = w * 32 + m * 16 + fq4 + r;
        S1[((size_t)g * 128 + i) * 128 + n * 16 + fr] = acc[m][n][r];
      }
}

// ---------------------------------------------------------------------------
// rel_fused, asymmetric-cache edition. Copy-pattern streaming (R9) kept.
// rq (exactly 256 MB) uses NORMAL loads -> allocates in the 256 MB Infinity
// Cache and becomes ~100% LLC hits across graph replays. rv keeps NT loads
// (no L3 allocation) -> its 256 MB streams HBM sequentially and cannot evict
// rq. The two halves drain concurrently from different memory tiers:
// time ~ max(rv@HBM ~4.5 TB/s, rq@L3 >=10 TB/s) instead of 512 MB serial.
// ---------------------------------------------------------------------------
__global__ __launch_bounds__(256) void rel_fused(
    const float* __restrict__ q, const float* __restrict__ v,
    const float* __restrict__ rq, const float* __restrict__ rv,
    const float* __restrict__ S1, float* __restrict__ attn,
    float* __restrict__ v2) {
  const int g = blockIdx.x;
  const int i = blockIdx.y;
  const int t = threadIdx.x;
  const int w = t >> 6;
  const int l = t & 63;
  const int c = t & 31;     // f4 column within row
  const int rlow = t >> 5;  // row & 7 served by this thread (0..7)

  __shared__ float logits[L];
  __shared__ float vacc_s[L];

  const size_t gi = (size_t)g * L + i;
  const f4 qf = *(const f4*)&q[gi * 128 + c * 4];
  const f4 vf = *(const f4*)&v[gi * 128 + c * 4];

  const f4* rqp = (const f4*)(rq + gi * 16384);
  const f4* rvp = (const f4*)(rv + gi * 16384);

  float aq[16], av[16];
#pragma unroll
  for (int k = 0; k < 16; k++) {
    const f4 d = rqp[t + 256 * k];  // normal load: allocate in L3 (fits!)
    aq[k] = qf.x * d.x + qf.y * d.y + qf.z * d.z + qf.w * d.w;
  }
#pragma unroll
  for (int k = 0; k < 16; k++) {
    const f4 d = __builtin_nontemporal_load(&rvp[t + 256 * k]);  // nt: stream
    av[k] = vf.x * d.x + vf.y * d.y + vf.z * d.z + vf.w * d.w;
  }

#pragma unroll
  for (int mask = 1; mask <= 16; mask <<= 1) {
#pragma unroll
    for (int k = 0; k < 16; k++) {
      aq[k] += __shfl_xor(aq[k], mask);
      av[k] += __shfl_xor(av[k], mask);
    }
  }
  if (c == 0) {
#pragma unroll
    for (int k = 0; k < 16; k++) {
      const int row = 8 * k + rlow;
      logits[row] = aq[k];
      vacc_s[row] = av[k];
    }
  }

  __syncthreads();
  if (w == 0) {
    const float* S1p = S1 + gi * 128;
    const float x0 = (logits[l] + S1p[l]) * 0.25f;       // scale = 0.25
    const float x1 = (logits[l + 64] + S1p[l + 64]) * 0.25f;
    float m = fmaxf(x0, x1);
#pragma unroll
    for (int mask = 1; mask <= 32; mask <<= 1) m = fmaxf(m, __shfl_xor(m, mask));
    const float e0 = __expf(x0 - m);
    const float e1 = __expf(x1 - m);
    float ssum = e0 + e1;
#pragma unroll
    for (int mask = 1; mask <= 32; mask <<= 1) ssum += __shfl_xor(ssum, mask);
    const float inv = 1.0f / ssum;
    attn[gi * 128 + l] = e0 * inv;
    attn[gi * 128 + l + 64] = e1 * inv;
  }
  if (t < 128) v2[gi * 128 + t] = v[gi * 128 + t] + vacc_s[t];
}

// ---------------------------------------------------------------------------
// ctx[g,i,:] = sum_j attn[g,i,j] * v2[g,j,:], written as bf16 FLAT
// (ctx_flat[gi*128+dd]) — identical memory layout to the [512][1024] view.
// ---------------------------------------------------------------------------
__global__ __launch_bounds__(256) void context_k(const float* __restrict__ attn,
                                                 const float* __restrict__ v2,
                                                 unsigned short* __restrict__ ctxb) {
  const int g = blockIdx.x;
  const int i = blockIdx.y;
  const int t = threadIdx.x;
  const int dd = t & 127;
  const int h = t >> 7;
  __shared__ float arow[L];
  __shared__ float part[128];
  const size_t gi = (size_t)g * L + i;
  if (t < L) arow[t] = attn[gi * 128 + t];
  __syncthreads();
  float acc = 0.f;
  const float* v2g = v2 + (size_t)g * (L * 128);
#pragma unroll 8
  for (int j = h * 64; j < h * 64 + 64; j++)
    acc = fmaf(arow[j], v2g[j * 128 + dd], acc);
  if (h == 1) part[dd] = acc;
  __syncthreads();
  if (h == 0) ctxb[gi * 128 + dd] = f2bf(acc + part[dd]);
}

// ---------------------------------------------------------------------------
// out = LayerNorm(pre + residual) * gamma + beta
// ---------------------------------------------------------------------------
__global__ __launch_bounds__(256) void resid_ln(const float* __restrict__ pre,
                                                const float* __restrict__ resid,
                                                const float* __restrict__ gamma,
                                                const float* __restrict__ beta,
                                                float* __restrict__ out) {
  const int r = blockIdx.x;
  const int t = threadIdx.x;
  const float4 p = *(const float4*)&pre[(size_t)r * MD + t * 4];
  const float4 rs = *(const float4*)&resid[(size_t)r * MD + t * 4];
  float4 x;
  x.x = p.x + rs.x; x.y = p.y + rs.y; x.z = p.z + rs.z; x.w = p.w + rs.w;
  float s = x.x + x.y + x.z + x.w;
  float ss = x.x * x.x + x.y * x.y + x.z * x.z + x.w * x.w;
#pragma unroll
  for (int mask = 1; mask <= 32; mask <<= 1) {
    s += __shfl_xor(s, mask);
    ss += __shfl_xor(ss, mask);
  }
  __shared__ float as_[4], aq_[4];
  const int w = t >> 6;
  if ((t & 63) == 0) { as_[w] = s; aq_[w] = ss; }
  __syncthreads();
  s = as_[0] + as_[1] + as_[2] + as_[3];
  ss = aq_[0] + aq_[1] + aq_[2] + aq_[3];
  const float mu = s * (1.0f / 1024.0f);
  const float var = ss * (1.0f / 1024.0f) - mu * mu;
  const float inv = rsqrtf(var + LN_EPS);
  const float4 g4 = *(const float4*)&gamma[t * 4];
  const float4 b4 = *(const float4*)&beta[t * 4];
  float4 o;
  o.x = (x.x - mu) * inv * g4.x + b4.x;
  o.y = (x.y - mu) * inv * g4.y + b4.y;
  o.z = (x.z - mu) * inv * g4.z + b4.z;
  o.w = (x.w - mu) * inv * g4.w + b4.w;
  *(float4*)&out[(size_t)r * MD + t * 4] = o;
}

extern "C" void kernel_launch(void* const* d_in, const int* in_sizes, int n_in,
                              void* d_out, int out_size, void* d_ws,
                              size_t ws_size, hipStream_t stream) {
  (void)in_sizes; (void)n_in; (void)out_size; (void)ws_size;
  const float* key = (const float*)d_in[0];
  const float* value = (const float*)d_in[1];
  const float* query = (const float*)d_in[2];
  const float* rq = (const float*)d_in[3];
  const float* rv = (const float*)d_in[4];
  const float* Wq = (const float*)d_in[5];
  const float* bq = (const float*)d_in[6];
  const float* Wk = (const float*)d_in[7];
  const float* bk = (const float*)d_in[8];
  const float* Wv = (const float*)d_in[9];
  const float* bv = (const float*)d_in[10];
  const float* Wo = (const float*)d_in[11];
  const float* bo = (const float*)d_in[12];
  const float* gamma = (const float*)d_in[13];
  const float* beta = (const float*)d_in[14];

  float* out0 = (float*)d_out;               // [4,128,1024]
  float* attn_out = (float*)d_out + 524288;  // [32,128,128]

  float* ws = (float*)d_ws;
  float* q_ws = ws;                    // fp32 [512][1024]
  float* k_ws = ws + 524288;           // (unused fp32 k — kept for layout)
  float* v_ws = ws + 2 * 524288;
  float* v2_ws = ws + 3 * 524288;
  float* pre_ws = ws + 4 * 524288;
  float* S1_ws = ws + 5 * 524288;      // [32][128][128] fp32
  unsigned short* us = (unsigned short*)(ws + 6 * 524288);
  unsigned short* qb = us;             // bf16 [512][1024] each
  unsigned short* kb = us + 524288;
  unsigned short* inqb = us + 2 * 524288;
  unsigned short* inkb = us + 3 * 524288;
  unsigned short* invb = us + 4 * 524288;
  unsigned short* ctxb = us + 5 * 524288;
  unsigned short* Wqb = us + 6 * 524288;   // bf16 [1024][1024] each
  unsigned short* Wkb = Wqb + 1048576;
  unsigned short* Wvb = Wkb + 1048576;
  unsigned short* Wob = Wvb + 1048576;

  cvt_bf16<<<dim3(512, 1, 7), 256, 0, stream>>>(query, key, value, Wq, Wk, Wv,
                                                Wo, inqb, inkb, invb, Wqb, Wkb,
                                                Wvb, Wob);
  qkv_mfma<<<dim3(8, 16, 3), 256, 0, stream>>>(inqb, inkb, invb, Wqb, Wkb, Wvb,
                                               bq, bk, bv, q_ws, k_ws, v_ws,
                                               qb, kb);
  qk_mfma<<<32, 256, 0, stream>>>(qb, kb, S1_ws);
  rel_fused<<<dim3(32, 128), 256, 0, stream>>>(q_ws, v_ws, rq, rv, S1_ws,
                                               attn_out, v2_ws);
  context_k<<<dim3(32, 128), 256, 0, stream>>>(attn_out, v2_ws, ctxb);
  o_mfma<<<dim3(8, 16), 256, 0, stream>>>(ctxb, Wob, bo, pre_ws);
  resid_ln<<<512, 256, 0, stream>>>(pre_ws, query, gamma, beta, out0);
}

// Round 11
// 150.370 us; speedup vs baseline: 1.0065x; 1.0065x over previous
//
#include <hip/hip_runtime.h>

#define MD 1024
#define L 128
#define LN_EPS 1e-5f

typedef __attribute__((ext_vector_type(8))) short bh8;   // 8 x bf16 (4 VGPR)
typedef __attribute__((ext_vector_type(4))) float fx4;   // MFMA accumulator
typedef __attribute__((ext_vector_type(4))) float f4;    // vector float4

__device__ __forceinline__ unsigned short f2bf(float x) {
  unsigned int u = __float_as_uint(x);
  u = (u + 0x7FFFu + ((u >> 16) & 1u)) >> 16;  // RNE
  return (unsigned short)u;
}

// ---------------------------------------------------------------------------
// fp32 -> bf16 convert: z picks array {query,key,value,Wq,Wk,Wv,Wo}
// ---------------------------------------------------------------------------
__global__ __launch_bounds__(256) void cvt_bf16(
    const float* s0, const float* s1, const float* s2, const float* s3,
    const float* s4, const float* s5, const float* s6, unsigned short* d0,
    unsigned short* d1, unsigned short* d2, unsigned short* d3,
    unsigned short* d4, unsigned short* d5, unsigned short* d6) {
  const float* s;
  unsigned short* d;
  int n;
  switch (blockIdx.z) {
    case 0: s = s0; d = d0; n = 524288; break;
    case 1: s = s1; d = d1; n = 524288; break;
    case 2: s = s2; d = d2; n = 524288; break;
    case 3: s = s3; d = d3; n = 1048576; break;
    case 4: s = s4; d = d4; n = 1048576; break;
    case 5: s = s5; d = d5; n = 1048576; break;
    default: s = s6; d = d6; n = 1048576; break;
  }
  const int idx = (blockIdx.x * 256 + threadIdx.x) * 8;
  if (idx < n) {
    const float4 a = *(const float4*)&s[idx];
    const float4 b = *(const float4*)&s[idx + 4];
    uint4 o;
    o.x = (unsigned int)f2bf(a.x) | ((unsigned int)f2bf(a.y) << 16);
    o.y = (unsigned int)f2bf(a.z) | ((unsigned int)f2bf(a.w) << 16);
    o.z = (unsigned int)f2bf(b.x) | ((unsigned int)f2bf(b.y) << 16);
    o.w = (unsigned int)f2bf(b.z) | ((unsigned int)f2bf(b.w) << 16);
    *(uint4*)&d[idx] = o;
  }
}

// ---------------------------------------------------------------------------
// bf16 MFMA GEMM: out[r][c] = sum_m A[r][m] * W[c][m] + bias[c]
// ---------------------------------------------------------------------------
__device__ __forceinline__ void mfma_gemm_body(
    const unsigned short* __restrict__ A, const unsigned short* __restrict__ W,
    const float* __restrict__ bias, float* __restrict__ out,
    unsigned short* __restrict__ outb) {
  __shared__ short As[64][40];
  __shared__ short Bs[64][40];
  const int t = threadIdx.x;
  const int row0 = blockIdx.x * 64;
  const int col0 = blockIdx.y * 64;
  const int l = t & 63;
  const int w = t >> 6;
  const int wr = (w >> 1) * 32;
  const int wc = (w & 1) * 32;
  const int srow = t >> 2;       // 0..63
  const int skg = (t & 3) * 8;   // 0,8,16,24
  const int fr = l & 15;
  const int fq = (l >> 4) * 8;

  fx4 z = {0.f, 0.f, 0.f, 0.f};
  fx4 acc[2][2];
  acc[0][0] = z; acc[0][1] = z; acc[1][0] = z; acc[1][1] = z;

  for (int k0 = 0; k0 < MD; k0 += 32) {
    const uint4 av = *(const uint4*)&A[(size_t)(row0 + srow) * MD + k0 + skg];
    const uint4 bv = *(const uint4*)&W[(size_t)(col0 + srow) * MD + k0 + skg];
    __syncthreads();
    *(uint4*)&As[srow][skg] = av;
    *(uint4*)&Bs[srow][skg] = bv;
    __syncthreads();
    const bh8 a0 = *(const bh8*)&As[wr + fr][fq];
    const bh8 a1 = *(const bh8*)&As[wr + 16 + fr][fq];
    const bh8 b0 = *(const bh8*)&Bs[wc + fr][fq];
    const bh8 b1 = *(const bh8*)&Bs[wc + 16 + fr][fq];
    acc[0][0] = __builtin_amdgcn_mfma_f32_16x16x32_bf16(a0, b0, acc[0][0], 0, 0, 0);
    acc[0][1] = __builtin_amdgcn_mfma_f32_16x16x32_bf16(a0, b1, acc[0][1], 0, 0, 0);
    acc[1][0] = __builtin_amdgcn_mfma_f32_16x16x32_bf16(a1, b0, acc[1][0], 0, 0, 0);
    acc[1][1] = __builtin_amdgcn_mfma_f32_16x16x32_bf16(a1, b1, acc[1][1], 0, 0, 0);
  }

  const int fq4 = (l >> 4) * 4;
#pragma unroll
  for (int m = 0; m < 2; m++)
#pragma unroll
    for (int n = 0; n < 2; n++) {
      const int col = col0 + wc + n * 16 + fr;
      const float bval = bias[col];
#pragma unroll
      for (int r = 0; r < 4; r++) {
        const int row = row0 + wr + m * 16 + fq4 + r;
        const float v = acc[m][n][r] + bval;
        if (out) out[(size_t)row * MD + col] = v;
        if (outb) outb[(size_t)row * MD + col] = f2bf(v);
      }
    }
}

__global__ __launch_bounds__(256) void qkv_mfma(
    const unsigned short* Aq, const unsigned short* Ak,
    const unsigned short* Av, const unsigned short* Wq,
    const unsigned short* Wk, const unsigned short* Wv, const float* bq,
    const float* bk, const float* bv, float* qo, float* ko, float* vo,
    unsigned short* qb, unsigned short* kb) {
  if (blockIdx.z == 0) mfma_gemm_body(Aq, Wq, bq, qo, qb);
  else if (blockIdx.z == 1) mfma_gemm_body(Ak, Wk, bk, ko, kb);
  else mfma_gemm_body(Av, Wv, bv, vo, nullptr);
}

__global__ __launch_bounds__(256) void o_mfma(const unsigned short* A,
                                              const unsigned short* W,
                                              const float* bias, float* out) {
  mfma_gemm_body(A, W, bias, out, nullptr);
}

// ---------------------------------------------------------------------------
// S1[g,i,j] = sum_d q[g,i,d]*k[g,j,d], one block per g (flat reshape view).
// ---------------------------------------------------------------------------
__global__ __launch_bounds__(256) void qk_mfma(const unsigned short* __restrict__ qb,
                                               const unsigned short* __restrict__ kb,
                                               float* __restrict__ S1) {
  __shared__ short Qs[128][40];
  __shared__ short Ks[128][40];
  const int g = blockIdx.x;
  const int t = threadIdx.x;
  const int l = t & 63;
  const int w = t >> 6;
  const unsigned short* qg = qb + (size_t)g * 16384;
  const unsigned short* kg = kb + (size_t)g * 16384;
  const int srow = t >> 1;        // 0..127
  const int sh = (t & 1) * 16;    // 0 / 16
  const int fr = l & 15;
  const int fq = (l >> 4) * 8;

  fx4 z = {0.f, 0.f, 0.f, 0.f};
  fx4 acc[2][8];
#pragma unroll
  for (int m = 0; m < 2; m++)
#pragma unroll
    for (int n = 0; n < 8; n++) acc[m][n] = z;

  for (int d0 = 0; d0 < 128; d0 += 32) {
    const size_t off = (size_t)srow * 128 + d0 + sh;
    const uint4 q0 = *(const uint4*)&qg[off];
    const uint4 q1 = *(const uint4*)&qg[off + 8];
    const uint4 k0 = *(const uint4*)&kg[off];
    const uint4 k1 = *(const uint4*)&kg[off + 8];
    __syncthreads();
    *(uint4*)&Qs[srow][sh] = q0;
    *(uint4*)&Qs[srow][sh + 8] = q1;
    *(uint4*)&Ks[srow][sh] = k0;
    *(uint4*)&Ks[srow][sh + 8] = k1;
    __syncthreads();
    const bh8 a0 = *(const bh8*)&Qs[w * 32 + fr][fq];
    const bh8 a1 = *(const bh8*)&Qs[w * 32 + 16 + fr][fq];
#pragma unroll
    for (int n = 0; n < 8; n++) {
      const bh8 b = *(const bh8*)&Ks[n * 16 + fr][fq];
      acc[0][n] = __builtin_amdgcn_mfma_f32_16x16x32_bf16(a0, b, acc[0][n], 0, 0, 0);
      acc[1][n] = __builtin_amdgcn_mfma_f32_16x16x32_bf16(a1, b, acc[1][n], 0, 0, 0);
    }
  }

  const int fq4 = (l >> 4) * 4;
#pragma unroll
  for (int m = 0; m < 2; m++)
#pragma unroll
    for (int n = 0; n < 8; n++)
#pragma unroll
      for (int r = 0; r < 4; r++) {
        const int i = w * 32 + m * 16 + fq4 + r;
        S1[((size_t)g * 128 + i) * 128 + n * 16 + fr] = acc[m][n][r];
      }
}

// ---------------------------------------------------------------------------
// rel_fused, XCD-sequential-sweep edition. R9 copy-pattern + nt loads kept;
// NEW: bijective XCD-chunked slab swizzle. Dispatch-linear block n maps to
// slab s = (n&7)*512 + (n>>3)  (4096%8==0 -> bijective), so XCD k streams
// the contiguous 32 MB region [k*32MB,(k+1)*32MB) of rq/rv IN ORDER — the
// same device-level address walk as the 7 TB/s fill kernels. Tests whether
// the ~4.2 TB/s read cap (invariant across R6-R10 load structures) is
// DRAM/fabric page locality.
// ---------------------------------------------------------------------------
__global__ __launch_bounds__(256) void rel_fused(
    const float* __restrict__ q, const float* __restrict__ v,
    const float* __restrict__ rq, const float* __restrict__ rv,
    const float* __restrict__ S1, float* __restrict__ attn,
    float* __restrict__ v2) {
  const int n = blockIdx.x + 32 * blockIdx.y;  // dispatch-linear id 0..4095
  const int s = (n & 7) * 512 + (n >> 3);      // XCD-chunked sequential slab
  const int g = s >> 7;
  const int i = s & 127;
  const int t = threadIdx.x;
  const int w = t >> 6;
  const int l = t & 63;
  const int c = t & 31;     // f4 column within row
  const int rlow = t >> 5;  // row & 7 served by this thread (0..7)

  __shared__ float logits[L];
  __shared__ float vacc_s[L];

  const size_t gi = (size_t)g * L + i;
  const f4 qf = *(const f4*)&q[gi * 128 + c * 4];
  const f4 vf = *(const f4*)&v[gi * 128 + c * 4];

  const f4* rqp = (const f4*)(rq + gi * 16384);
  const f4* rvp = (const f4*)(rv + gi * 16384);

  float aq[16], av[16];
#pragma unroll
  for (int k = 0; k < 16; k++) {
    const f4 d = __builtin_nontemporal_load(&rqp[t + 256 * k]);
    aq[k] = qf.x * d.x + qf.y * d.y + qf.z * d.z + qf.w * d.w;
  }
#pragma unroll
  for (int k = 0; k < 16; k++) {
    const f4 d = __builtin_nontemporal_load(&rvp[t + 256 * k]);
    av[k] = vf.x * d.x + vf.y * d.y + vf.z * d.z + vf.w * d.w;
  }

#pragma unroll
  for (int mask = 1; mask <= 16; mask <<= 1) {
#pragma unroll
    for (int k = 0; k < 16; k++) {
      aq[k] += __shfl_xor(aq[k], mask);
      av[k] += __shfl_xor(av[k], mask);
    }
  }
  if (c == 0) {
#pragma unroll
    for (int k = 0; k < 16; k++) {
      const int row = 8 * k + rlow;
      logits[row] = aq[k];
      vacc_s[row] = av[k];
    }
  }

  __syncthreads();
  if (w == 0) {
    const float* S1p = S1 + gi * 128;
    const float x0 = (logits[l] + S1p[l]) * 0.25f;       // scale = 0.25
    const float x1 = (logits[l + 64] + S1p[l + 64]) * 0.25f;
    float m = fmaxf(x0, x1);
#pragma unroll
    for (int mask = 1; mask <= 32; mask <<= 1) m = fmaxf(m, __shfl_xor(m, mask));
    const float e0 = __expf(x0 - m);
    const float e1 = __expf(x1 - m);
    float ssum = e0 + e1;
#pragma unroll
    for (int mask = 1; mask <= 32; mask <<= 1) ssum += __shfl_xor(ssum, mask);
    const float inv = 1.0f / ssum;
    attn[gi * 128 + l] = e0 * inv;
    attn[gi * 128 + l + 64] = e1 * inv;
  }
  if (t < 128) v2[gi * 128 + t] = v[gi * 128 + t] + vacc_s[t];
}

// ---------------------------------------------------------------------------
// ctx[g,i,:] = sum_j attn[g,i,j] * v2[g,j,:], written as bf16 FLAT.
// ---------------------------------------------------------------------------
__global__ __launch_bounds__(256) void context_k(const float* __restrict__ attn,
                                                 const float* __restrict__ v2,
                                                 unsigned short* __restrict__ ctxb) {
  const int g = blockIdx.x;
  const int i = blockIdx.y;
  const int t = threadIdx.x;
  const int dd = t & 127;
  const int h = t >> 7;
  __shared__ float arow[L];
  __shared__ float part[128];
  const size_t gi = (size_t)g * L + i;
  if (t < L) arow[t] = attn[gi * 128 + t];
  __syncthreads();
  float acc = 0.f;
  const float* v2g = v2 + (size_t)g * (L * 128);
#pragma unroll 8
  for (int j = h * 64; j < h * 64 + 64; j++)
    acc = fmaf(arow[j], v2g[j * 128 + dd], acc);
  if (h == 1) part[dd] = acc;
  __syncthreads();
  if (h == 0) ctxb[gi * 128 + dd] = f2bf(acc + part[dd]);
}

// ---------------------------------------------------------------------------
// out = LayerNorm(pre + residual) * gamma + beta
// ---------------------------------------------------------------------------
__global__ __launch_bounds__(256) void resid_ln(const float* __restrict__ pre,
                                                const float* __restrict__ resid,
                                                const float* __restrict__ gamma,
                                                const float* __restrict__ beta,
                                                float* __restrict__ out) {
  const int r = blockIdx.x;
  const int t = threadIdx.x;
  const float4 p = *(const float4*)&pre[(size_t)r * MD + t * 4];
  const float4 rs = *(const float4*)&resid[(size_t)r * MD + t * 4];
  float4 x;
  x.x = p.x + rs.x; x.y = p.y + rs.y; x.z = p.z + rs.z; x.w = p.w + rs.w;
  float s = x.x + x.y + x.z + x.w;
  float ss = x.x * x.x + x.y * x.y + x.z * x.z + x.w * x.w;
#pragma unroll
  for (int mask = 1; mask <= 32; mask <<= 1) {
    s += __shfl_xor(s, mask);
    ss += __shfl_xor(ss, mask);
  }
  __shared__ float as_[4], aq_[4];
  const int w = t >> 6;
  if ((t & 63) == 0) { as_[w] = s; aq_[w] = ss; }
  __syncthreads();
  s = as_[0] + as_[1] + as_[2] + as_[3];
  ss = aq_[0] + aq_[1] + aq_[2] + aq_[3];
  const float mu = s * (1.0f / 1024.0f);
  const float var = ss * (1.0f / 1024.0f) - mu * mu;
  const float inv = rsqrtf(var + LN_EPS);
  const float4 g4 = *(const float4*)&gamma[t * 4];
  const float4 b4 = *(const float4*)&beta[t * 4];
  float4 o;
  o.x = (x.x - mu) * inv * g4.x + b4.x;
  o.y = (x.y - mu) * inv * g4.y + b4.y;
  o.z = (x.z - mu) * inv * g4.z + b4.z;
  o.w = (x.w - mu) * inv * g4.w + b4.w;
  *(float4*)&out[(size_t)r * MD + t * 4] = o;
}

extern "C" void kernel_launch(void* const* d_in, const int* in_sizes, int n_in,
                              void* d_out, int out_size, void* d_ws,
                              size_t ws_size, hipStream_t stream) {
  (void)in_sizes; (void)n_in; (void)out_size; (void)ws_size;
  const float* key = (const float*)d_in[0];
  const float* value = (const float*)d_in[1];
  const float* query = (const float*)d_in[2];
  const float* rq = (const float*)d_in[3];
  const float* rv = (const float*)d_in[4];
  const float* Wq = (const float*)d_in[5];
  const float* bq = (const float*)d_in[6];
  const float* Wk = (const float*)d_in[7];
  const float* bk = (const float*)d_in[8];
  const float* Wv = (const float*)d_in[9];
  const float* bv = (const float*)d_in[10];
  const float* Wo = (const float*)d_in[11];
  const float* bo = (const float*)d_in[12];
  const float* gamma = (const float*)d_in[13];
  const float* beta = (const float*)d_in[14];

  float* out0 = (float*)d_out;               // [4,128,1024]
  float* attn_out = (float*)d_out + 524288;  // [32,128,128]

  float* ws = (float*)d_ws;
  float* q_ws = ws;                    // fp32 [512][1024]
  float* k_ws = ws + 524288;           // (unused fp32 k — kept for layout)
  float* v_ws = ws + 2 * 524288;
  float* v2_ws = ws + 3 * 524288;
  float* pre_ws = ws + 4 * 524288;
  float* S1_ws = ws + 5 * 524288;      // [32][128][128] fp32
  unsigned short* us = (unsigned short*)(ws + 6 * 524288);
  unsigned short* qb = us;             // bf16 [512][1024] each
  unsigned short* kb = us + 524288;
  unsigned short* inqb = us + 2 * 524288;
  unsigned short* inkb = us + 3 * 524288;
  unsigned short* invb = us + 4 * 524288;
  unsigned short* ctxb = us + 5 * 524288;
  unsigned short* Wqb = us + 6 * 524288;   // bf16 [1024][1024] each
  unsigned short* Wkb = Wqb + 1048576;
  unsigned short* Wvb = Wkb + 1048576;
  unsigned short* Wob = Wvb + 1048576;

  cvt_bf16<<<dim3(512, 1, 7), 256, 0, stream>>>(query, key, value, Wq, Wk, Wv,
                                                Wo, inqb, inkb, invb, Wqb, Wkb,
                                                Wvb, Wob);
  qkv_mfma<<<dim3(8, 16, 3), 256, 0, stream>>>(inqb, inkb, invb, Wqb, Wkb, Wvb,
                                               bq, bk, bv, q_ws, k_ws, v_ws,
                                               qb, kb);
  qk_mfma<<<32, 256, 0, stream>>>(qb, kb, S1_ws);
  rel_fused<<<dim3(32, 128), 256, 0, stream>>>(q_ws, v_ws, rq, rv, S1_ws,
                                               attn_out, v2_ws);
  context_k<<<dim3(32, 128), 256, 0, stream>>>(attn_out, v2_ws, ctxb);
  o_mfma<<<dim3(8, 16), 256, 0, stream>>>(ctxb, Wob, bo, pre_ws);
  resid_ln<<<512, 256, 0, stream>>>(pre_ws, query, gamma, beta, out0);
}